// Round 1
// baseline (226.047 us; speedup 1.0000x reference)
//
#include <hip/hip_runtime.h>
#include <hip/hip_fp16.h>

typedef _Float16 half8_t __attribute__((ext_vector_type(8)));
typedef _Float16 half4_t __attribute__((ext_vector_type(4)));
typedef float f32x4 __attribute__((ext_vector_type(4)));

// ws layout: [0, 55296) w1T fp16 [288][96] (permuted cols: j' = K*96 + c, orig col = c*3+K)
//            [55296, 73728) w2T fp16 [96][96] (transposed)
//            [73728, 74880) b1p f32 [288] (permuted)
#define WS_W2T_OFF 55296
#define WS_B1P_OFF 73728

__global__ __launch_bounds__(256) void swin_prep_kernel(
    const float* __restrict__ w1, const float* __restrict__ b1,
    const float* __restrict__ w2,
    _Float16* __restrict__ w1T, _Float16* __restrict__ w2T,
    float* __restrict__ b1p)
{
    int idx = blockIdx.x * 256 + threadIdx.x;
    if (idx < 27648) {
        int jp = idx / 96, k = idx % 96;
        int jo = (jp % 96) * 3 + (jp / 96);      // original col in w1
        w1T[idx] = (_Float16)w1[k * 288 + jo];   // w1T[j'][k]
    } else if (idx < 27648 + 9216) {
        int i2 = idx - 27648;
        int n = i2 / 96, k = i2 % 96;
        w2T[i2] = (_Float16)w2[k * 96 + n];      // w2T[n][k]
    } else if (idx < 27648 + 9216 + 288) {
        int jp = idx - 27648 - 9216;
        b1p[jp] = b1[(jp % 96) * 3 + (jp / 96)];
    }
}

// One block = one (batch, window_row, window_col). 256 threads = 4 waves.
// LDS union (63744 B):
//   [0,16640)      : phase0/1: xb fp16 [64][104] ; phase2: S f32 [64][65]
//                    (S cols 49..52 red_max, 53..56 red_sum, 57 = 1/rowsum)
//   [16640,54528)  : qkv fp16 [64][296]  (cols: q = h*32+e, k = 96+h*32+e, v = 192+h*32+e)
//   [54528,63744)  : P fp16 [64][72] ; aliased O fp16 [64][40] (barrier-separated)
__global__ __launch_bounds__(256, 2) void swin_attn_kernel(
    const float* __restrict__ x,
    const _Float16* __restrict__ w1T,
    const _Float16* __restrict__ w2T,
    const float* __restrict__ b1p,
    const float* __restrict__ b2,
    const float* __restrict__ relb,
    float* __restrict__ out)
{
    __shared__ __align__(16) char smem[63744];
    float*     Sb  = (float*)smem;
    _Float16*  xb  = (_Float16*)smem;
    _Float16*  qkv = (_Float16*)(smem + 16640);
    _Float16*  Pb  = (_Float16*)(smem + 54528);
    _Float16*  Ob  = (_Float16*)(smem + 54528);

    const int tid = threadIdx.x;
    const int wv = tid >> 6;
    const int lane = tid & 63;
    const int lr = lane & 15;   // fragment row/col within 16
    const int lg = lane >> 4;   // k-group 0..3

    const int gid = blockIdx.x;
    const int b  = gid >> 6;
    const int wh = (gid >> 3) & 7;
    const int ww = gid & 7;

    const f32x4 fz = {0.f, 0.f, 0.f, 0.f};

    // ---- phase 0: gather rolled x window -> xb fp16 (rows 49..63 zeroed) ----
    {
        const int p = tid >> 2, sub = tid & 3;
        const float* xrow = nullptr;
        if (p < 49) {
            int m1 = p / 7, m2 = p % 7;
            int rr = (wh * 7 + m1 + 4) % 56;   // roll by -4
            int cc = (ww * 7 + m2 + 4) % 56;
            xrow = x + ((size_t)b * 3136 + rr * 56 + cc) * 96;
        }
        #pragma unroll
        for (int j = 0; j < 6; ++j) {
            int e = sub * 24 + j * 4;
            half4_t hv = {(_Float16)0.f, (_Float16)0.f, (_Float16)0.f, (_Float16)0.f};
            if (p < 49) {
                const float4 v = *(const float4*)(xrow + e);
                hv[0] = (_Float16)v.x; hv[1] = (_Float16)v.y;
                hv[2] = (_Float16)v.z; hv[3] = (_Float16)v.w;
            }
            *(half4_t*)(xb + p * 104 + e) = hv;
        }
    }
    __syncthreads();

    // ---- phase 1: qkv = xb @ w1T^T + b1p  (72 16x16 tiles, K=96) ----
    for (int t = wv; t < 72; t += 4) {
        const int mt = t / 18, nt = t % 18;
        f32x4 acc = fz;
        #pragma unroll
        for (int kt = 0; kt < 3; ++kt) {
            half8_t a  = *(const half8_t*)(xb  + (mt * 16 + lr) * 104 + kt * 32 + lg * 8);
            half8_t bb = *(const half8_t*)(w1T + (nt * 16 + lr) * 96  + kt * 32 + lg * 8);
            acc = __builtin_amdgcn_mfma_f32_16x16x32_f16(a, bb, acc, 0, 0, 0);
        }
        const int col = nt * 16 + lr;
        const float bv = b1p[col];
        const int r0 = mt * 16 + lg * 4;
        #pragma unroll
        for (int r = 0; r < 4; ++r)
            qkv[(r0 + r) * 296 + col] = (_Float16)(acc[r] + bv);
    }
    __syncthreads();

    f32x4 accO[2][4];
    #pragma unroll
    for (int i = 0; i < 2; ++i)
        #pragma unroll
        for (int m = 0; m < 4; ++m) accO[i][m] = fz;

    const bool mrow = (wh == 7), mcol = (ww == 7);

    for (int h = 0; h < 3; ++h) {
        // ---- 2a: S = q k^T / sqrt(32) + bias + masks ----
        for (int t = wv; t < 16; t += 4) {
            const int mt = t >> 2, nt = t & 3;
            half8_t qf = *(const half8_t*)(qkv + (mt * 16 + lr) * 296 + h * 32 + lg * 8);
            half8_t kf = *(const half8_t*)(qkv + (nt * 16 + lr) * 296 + 96 + h * 32 + lg * 8);
            f32x4 s = __builtin_amdgcn_mfma_f32_16x16x32_f16(qf, kf, fz, 0, 0, 0);
            const int col = nt * 16 + lr;
            if (col < 49) {
                #pragma unroll
                for (int r = 0; r < 4; ++r) {
                    const int row = mt * 16 + lg * 4 + r;
                    float v = s[r] * 0.17677669529663687f;
                    v += relb[(row < 49 ? row : 48) * 49 + col];
                    if (mrow && ((((row / 7) >= 4) ? 1 : 0) ^ (((col / 7) >= 4) ? 1 : 0))) v = -1e30f;
                    if (mcol && ((((row % 7) >= 4) ? 1 : 0) ^ (((col % 7) >= 4) ? 1 : 0))) v = -1e30f;
                    Sb[row * 65 + col] = v;
                }
            }
        }
        __syncthreads();
        // ---- 2b: row softmax (4 threads per row), P = exp(S - max) unnormalized ----
        {
            const int row = tid & 63, qd = tid >> 6;
            const int start = qd * 13;
            const int cnt = (qd < 3) ? 13 : 10;
            float pm = -3.4e38f;
            for (int i = 0; i < cnt; ++i) pm = fmaxf(pm, Sb[row * 65 + start + i]);
            Sb[row * 65 + 49 + qd] = pm;
            __syncthreads();
            const float rm = fmaxf(fmaxf(Sb[row * 65 + 49], Sb[row * 65 + 50]),
                                   fmaxf(Sb[row * 65 + 51], Sb[row * 65 + 52]));
            float ps = 0.f;
            for (int i = 0; i < cnt; ++i) {
                float e = __expf(Sb[row * 65 + start + i] - rm);
                ps += e;
                Pb[row * 72 + start + i] = (_Float16)e;
            }
            if (qd == 3)
                for (int c = 49; c < 64; ++c) Pb[row * 72 + c] = (_Float16)0.f;
            Sb[row * 65 + 53 + qd] = ps;
            __syncthreads();
            if (tid < 64) {
                float s4 = Sb[tid * 65 + 53] + Sb[tid * 65 + 54]
                         + Sb[tid * 65 + 55] + Sb[tid * 65 + 56];
                Sb[tid * 65 + 57] = 1.0f / s4;
            }
            __syncthreads();
        }
        // ---- 2c: O = (P V) * (1/rowsum)  (kept in regs) ----
        f32x4 oacc[2];
        for (int t = wv, i = 0; t < 8; t += 4, ++i) {
            const int mt = t >> 1, ne = t & 1;
            f32x4 acc = fz;
            #pragma unroll
            for (int kt = 0; kt < 2; ++kt) {
                half8_t pf = *(const half8_t*)(Pb + (mt * 16 + lr) * 72 + kt * 32 + lg * 8);
                half8_t vf;
                #pragma unroll
                for (int j = 0; j < 8; ++j)
                    vf[j] = qkv[(kt * 32 + lg * 8 + j) * 296 + 192 + h * 32 + ne * 16 + lr];
                acc = __builtin_amdgcn_mfma_f32_16x16x32_f16(pf, vf, acc, 0, 0, 0);
            }
            #pragma unroll
            for (int r = 0; r < 4; ++r)
                acc[r] *= Sb[(mt * 16 + lg * 4 + r) * 65 + 57];
            oacc[i] = acc;
        }
        __syncthreads();   // all P reads done before O overwrites the region
        // ---- 2d: O -> LDS ----
        for (int t = wv, i = 0; t < 8; t += 4, ++i) {
            const int mt = t >> 1, ne = t & 1;
            #pragma unroll
            for (int r = 0; r < 4; ++r)
                Ob[(mt * 16 + lg * 4 + r) * 40 + ne * 16 + lr] = (_Float16)oacc[i][r];
        }
        __syncthreads();
        // ---- 2e: accO += O @ w2[32h:32h+32, :]  (accumulated over heads) ----
        for (int nt = wv, ni = 0; nt < 6; nt += 4, ++ni) {
            #pragma unroll
            for (int mt = 0; mt < 4; ++mt) {
                half8_t of = *(const half8_t*)(Ob  + (mt * 16 + lr) * 40 + lg * 8);
                half8_t wf = *(const half8_t*)(w2T + (nt * 16 + lr) * 96 + h * 32 + lg * 8);
                accO[ni][mt] = __builtin_amdgcn_mfma_f32_16x16x32_f16(of, wf, accO[ni][mt], 0, 0, 0);
            }
        }
        // next head's 2a->2b barrier covers Ob-read vs Pb-write hazard
    }

    // ---- phase 3: out = accO + b2, store fp32 with +3 roll ----
    for (int nt = wv, ni = 0; nt < 6; nt += 4, ++ni) {
        const int colc = nt * 16 + lr;
        const float bv = b2[colc];
        #pragma unroll
        for (int mt = 0; mt < 4; ++mt) {
            #pragma unroll
            for (int r = 0; r < 4; ++r) {
                const int row = mt * 16 + lg * 4 + r;
                if (row < 49) {
                    const int m1 = row / 7, m2 = row % 7;
                    const int oi = (wh * 7 + m1 + 3) % 56;
                    const int oj = (ww * 7 + m2 + 3) % 56;
                    out[((size_t)b * 3136 + oi * 56 + oj) * 96 + colc] = accO[ni][mt][r] + bv;
                }
            }
        }
    }
}

extern "C" void kernel_launch(void* const* d_in, const int* in_sizes, int n_in,
                              void* d_out, int out_size, void* d_ws, size_t ws_size,
                              hipStream_t stream) {
    const float* x    = (const float*)d_in[0];
    const float* w1   = (const float*)d_in[1];
    const float* b1   = (const float*)d_in[2];
    const float* w2   = (const float*)d_in[3];
    const float* b2   = (const float*)d_in[4];
    const float* relb = (const float*)d_in[5];
    float* out = (float*)d_out;

    _Float16* w1T = (_Float16*)((char*)d_ws);
    _Float16* w2T = (_Float16*)((char*)d_ws + WS_W2T_OFF);
    float*    b1p = (float*)((char*)d_ws + WS_B1P_OFF);

    swin_prep_kernel<<<146, 256, 0, stream>>>(w1, b1, w2, w1T, w2T, b1p);
    swin_attn_kernel<<<4096, 256, 0, stream>>>(x, w1T, w2T, b1p, b2, relb, out);
}

// Round 2
// 132.663 us; speedup vs baseline: 1.7039x; 1.7039x over previous
//
#include <hip/hip_runtime.h>
#include <hip/hip_fp16.h>

typedef _Float16 half8_t __attribute__((ext_vector_type(8)));
typedef _Float16 half4_t __attribute__((ext_vector_type(4)));
typedef float f32x4 __attribute__((ext_vector_type(4)));

// ws: [0,55296)        w1T fp16 [288][96]  (q-rows pre-scaled by 1/sqrt(32))
//     [55296,73728)    w2T fp16 [96][96]
//     [73728,74880)    b1p f32 [288]       (q entries pre-scaled)
//     [74880,140416)   tbl f32 [4][64][64] (relbias + shift-mask + pad -1e30)
#define WS_W2T 55296
#define WS_B1P 73728
#define WS_TBL 74880

__global__ __launch_bounds__(256) void swin_prep_kernel(
    const float* __restrict__ w1, const float* __restrict__ b1,
    const float* __restrict__ w2, const float* __restrict__ relb,
    _Float16* __restrict__ w1T, _Float16* __restrict__ w2T,
    float* __restrict__ b1p, float* __restrict__ tbl)
{
    int idx = blockIdx.x * 256 + threadIdx.x;
    const float qs = 0.17677669529663687f;   // 1/sqrt(32)
    if (idx < 27648) {
        int jp = idx / 96, k = idx % 96;
        int jo = (jp % 96) * 3 + (jp / 96);      // original col in w1
        float v = w1[k * 288 + jo];
        if (jp < 96) v *= qs;                    // fold QK scale into Q
        w1T[idx] = (_Float16)v;
    } else if (idx < 36864) {
        int i2 = idx - 27648;
        int n = i2 / 96, k = i2 % 96;
        w2T[i2] = (_Float16)w2[k * 96 + n];
    } else if (idx < 37152) {
        int jp = idx - 36864;
        float v = b1[(jp % 96) * 3 + (jp / 96)];
        if (jp < 96) v *= qs;
        b1p[jp] = v;
    } else if (idx < 37152 + 16384) {
        int t = idx - 37152;
        int v = t >> 12, q = (t >> 6) & 63, k = t & 63;
        float val = -1e30f;
        if (q < 49 && k < 49) {
            val = relb[q * 49 + k];
            if ((v & 1) && ((q >= 28) != (k >= 28))) val = -1e30f;          // row mask
            if ((v & 2) && (((q % 7) >= 4) != ((k % 7) >= 4))) val = -1e30f; // col mask
        }
        tbl[t] = val;
    }
}

// One block = one (batch, wrow, wcol) window; 4 waves; wave wv owns q-rows [wv*16, wv*16+16).
// LDS (49664 B, 3 blocks/CU):
//   Qb [4][16][104] fp16  (per-wave Q rows, row-major)          @ 0
//   Kb [64][104]    fp16  (all K rows, row-major)               @ 13312
//   Vt [96][72]     fp16  (V transposed: [e][token])            @ 26624
//   Pb [4][16][72]  fp16  (per-wave P; aliased per-wave O[16][32] — wave-local,
//                          DS in-order per wave => no barriers)  @ 40448
__global__ __launch_bounds__(256, 3) void swin_attn_kernel(
    const float* __restrict__ x,
    const _Float16* __restrict__ w1T,
    const _Float16* __restrict__ w2T,
    const float* __restrict__ b1p,
    const float* __restrict__ b2,
    const float* __restrict__ tbl,
    float* __restrict__ out)
{
    __shared__ __align__(16) char smem[49664];
    _Float16* Qb = (_Float16*)smem;
    _Float16* Kb = (_Float16*)(smem + 13312);
    _Float16* Vt = (_Float16*)(smem + 26624);
    _Float16* Pb = (_Float16*)(smem + 40448);

    const int tid = threadIdx.x;
    const int wv = tid >> 6, lane = tid & 63;
    const int lr = lane & 15, lg = lane >> 4;

    const int gid = blockIdx.x;
    const int b = gid >> 6, wh = (gid >> 3) & 7, ww = gid & 7;
    const f32x4 fz = {0.f, 0.f, 0.f, 0.f};

    // ---- phase 1: A-frags of x straight from global (rolled gather), fp32->fp16 ----
    half8_t xa[3];
    {
        const int row = wv * 16 + lr;
        if (row < 49) {
            const int m1 = row / 7, m2 = row % 7;
            int rr = wh * 7 + m1 + 4; if (rr >= 56) rr -= 56;
            int cc = ww * 7 + m2 + 4; if (cc >= 56) cc -= 56;
            const float* xr = x + ((size_t)b * 3136 + rr * 56 + cc) * 96;
            #pragma unroll
            for (int kt = 0; kt < 3; ++kt) {
                const float4 a0 = *(const float4*)(xr + kt * 32 + lg * 8);
                const float4 a1 = *(const float4*)(xr + kt * 32 + lg * 8 + 4);
                half8_t h;
                h[0] = (_Float16)a0.x; h[1] = (_Float16)a0.y;
                h[2] = (_Float16)a0.z; h[3] = (_Float16)a0.w;
                h[4] = (_Float16)a1.x; h[5] = (_Float16)a1.y;
                h[6] = (_Float16)a1.z; h[7] = (_Float16)a1.w;
                xa[kt] = h;
            }
        } else {
            #pragma unroll
            for (int kt = 0; kt < 3; ++kt)
                #pragma unroll
                for (int j = 0; j < 8; ++j) xa[kt][j] = (_Float16)0.f;
        }
    }

    _Float16* Qw = Qb + wv * 1664;   // wave-local Q [16][104]
    _Float16* Pw = Pb + wv * 1152;   // wave-local P/O [16][72]

    // qkv GEMM: wave wv computes output rows [wv*16, +16) for all 288 cols
    #pragma unroll
    for (int nt = 0; nt < 6; ++nt) {          // Q cols 0..95
        f32x4 acc = fz;
        #pragma unroll
        for (int kt = 0; kt < 3; ++kt) {
            half8_t bf = *(const half8_t*)(w1T + (nt * 16 + lr) * 96 + kt * 32 + lg * 8);
            acc = __builtin_amdgcn_mfma_f32_16x16x32_f16(xa[kt], bf, acc, 0, 0, 0);
        }
        const int col = nt * 16 + lr;
        const float bv = b1p[col];
        #pragma unroll
        for (int r = 0; r < 4; ++r)
            Qw[(lg * 4 + r) * 104 + col] = (_Float16)(acc[r] + bv);
    }
    #pragma unroll
    for (int nt = 6; nt < 12; ++nt) {         // K cols 96..191
        f32x4 acc = fz;
        #pragma unroll
        for (int kt = 0; kt < 3; ++kt) {
            half8_t bf = *(const half8_t*)(w1T + (nt * 16 + lr) * 96 + kt * 32 + lg * 8);
            acc = __builtin_amdgcn_mfma_f32_16x16x32_f16(xa[kt], bf, acc, 0, 0, 0);
        }
        const int col = nt * 16 + lr;
        const float bv = b1p[col];
        #pragma unroll
        for (int r = 0; r < 4; ++r)
            Kb[(wv * 16 + lg * 4 + r) * 104 + (col - 96)] = (_Float16)(acc[r] + bv);
    }
    #pragma unroll
    for (int nt = 12; nt < 18; ++nt) {        // V cols 192..287 -> transposed
        f32x4 acc = fz;
        #pragma unroll
        for (int kt = 0; kt < 3; ++kt) {
            half8_t bf = *(const half8_t*)(w1T + (nt * 16 + lr) * 96 + kt * 32 + lg * 8);
            acc = __builtin_amdgcn_mfma_f32_16x16x32_f16(xa[kt], bf, acc, 0, 0, 0);
        }
        const int col = nt * 16 + lr;
        const float bv = b1p[col];
        half4_t hv;
        #pragma unroll
        for (int r = 0; r < 4; ++r) hv[r] = (_Float16)(acc[r] + bv);
        *(half4_t*)(Vt + (col - 192) * 72 + wv * 16 + lg * 4) = hv;
    }
    __syncthreads();   // the ONLY barrier: Kb/Vt become visible to all waves

    const float* tblv = tbl + (((wh == 7) ? 1 : 0) + ((ww == 7) ? 2 : 0)) * 4096;
    f32x4 accO[6];
    #pragma unroll
    for (int i = 0; i < 6; ++i) accO[i] = fz;

    for (int h = 0; h < 3; ++h) {
        // ---- S^T = K · Q^T : lane holds S[q=wv*16+lr][k = kt4*16+lg*4+r] ----
        half8_t qf = *(const half8_t*)(Qw + lr * 104 + h * 32 + lg * 8);
        f32x4 s[4];
        #pragma unroll
        for (int kt4 = 0; kt4 < 4; ++kt4) {
            half8_t kf = *(const half8_t*)(Kb + (kt4 * 16 + lr) * 104 + h * 32 + lg * 8);
            s[kt4] = __builtin_amdgcn_mfma_f32_16x16x32_f16(kf, qf, fz, 0, 0, 0);
        }
        const int q = wv * 16 + lr;
        #pragma unroll
        for (int kt4 = 0; kt4 < 4; ++kt4) {
            const float4 tv = *(const float4*)(tblv + q * 64 + kt4 * 16 + lg * 4);
            s[kt4][0] += tv.x; s[kt4][1] += tv.y; s[kt4][2] += tv.z; s[kt4][3] += tv.w;
        }
        // ---- wave-local softmax: in-lane 16-reduce + 2 shuffles ----
        float m = s[0][0];
        #pragma unroll
        for (int kt4 = 0; kt4 < 4; ++kt4)
            #pragma unroll
            for (int r = 0; r < 4; ++r) m = fmaxf(m, s[kt4][r]);
        m = fmaxf(m, __shfl_xor(m, 16));
        m = fmaxf(m, __shfl_xor(m, 32));
        float sum = 0.f;
        #pragma unroll
        for (int kt4 = 0; kt4 < 4; ++kt4)
            #pragma unroll
            for (int r = 0; r < 4; ++r) {
                const float e = __expf(s[kt4][r] - m);
                s[kt4][r] = e; sum += e;
            }
        sum += __shfl_xor(sum, 16);
        sum += __shfl_xor(sum, 32);
        const float inv = 1.0f / sum;
        #pragma unroll
        for (int kt4 = 0; kt4 < 4; ++kt4) {
            half4_t p;
            #pragma unroll
            for (int r = 0; r < 4; ++r) p[r] = (_Float16)(s[kt4][r] * inv);
            *(half4_t*)(Pw + lr * 72 + kt4 * 16 + lg * 4) = p;   // wave-local
        }
        // ---- PV: O[q][e] (wave-local; Vt B-frags contiguous) ----
        half8_t pf0 = *(const half8_t*)(Pw + lr * 72 + lg * 8);
        half8_t pf1 = *(const half8_t*)(Pw + lr * 72 + 32 + lg * 8);
        #pragma unroll
        for (int ne = 0; ne < 2; ++ne) {
            half8_t vf0 = *(const half8_t*)(Vt + (h * 32 + ne * 16 + lr) * 72 + lg * 8);
            half8_t vf1 = *(const half8_t*)(Vt + (h * 32 + ne * 16 + lr) * 72 + 32 + lg * 8);
            f32x4 o = __builtin_amdgcn_mfma_f32_16x16x32_f16(pf0, vf0, fz, 0, 0, 0);
            o = __builtin_amdgcn_mfma_f32_16x16x32_f16(pf1, vf1, o, 0, 0, 0);
            // O -> LDS over own P region (reads above already issued; DS in-order per wave)
            #pragma unroll
            for (int r = 0; r < 4; ++r)
                Pw[(lg * 4 + r) * 72 + ne * 16 + lr] = (_Float16)o[r];
        }
        // ---- out-proj slice: accO += O_h @ W2[h*32:+32, :]  (wave-local A) ----
        half8_t of = *(const half8_t*)(Pw + lr * 72 + lg * 8);
        #pragma unroll
        for (int nt = 0; nt < 6; ++nt) {
            half8_t wf = *(const half8_t*)(w2T + (nt * 16 + lr) * 96 + h * 32 + lg * 8);
            accO[nt] = __builtin_amdgcn_mfma_f32_16x16x32_f16(of, wf, accO[nt], 0, 0, 0);
        }
    }

    // ---- phase 3: store (+3,+3) rolled, bias ----
    float b2v[6];
    #pragma unroll
    for (int nt = 0; nt < 6; ++nt) b2v[nt] = b2[nt * 16 + lr];
    #pragma unroll
    for (int r = 0; r < 4; ++r) {
        const int row = wv * 16 + lg * 4 + r;
        if (row < 49) {
            const int m1 = row / 7, m2 = row % 7;
            int oi = wh * 7 + m1 + 3; if (oi >= 56) oi -= 56;
            int oj = ww * 7 + m2 + 3; if (oj >= 56) oj -= 56;
            float* op = out + ((size_t)b * 3136 + oi * 56 + oj) * 96;
            #pragma unroll
            for (int nt = 0; nt < 6; ++nt)
                op[nt * 16 + lr] = accO[nt][r] + b2v[nt];
        }
    }
}

extern "C" void kernel_launch(void* const* d_in, const int* in_sizes, int n_in,
                              void* d_out, int out_size, void* d_ws, size_t ws_size,
                              hipStream_t stream) {
    const float* x    = (const float*)d_in[0];
    const float* w1   = (const float*)d_in[1];
    const float* b1   = (const float*)d_in[2];
    const float* w2   = (const float*)d_in[3];
    const float* b2   = (const float*)d_in[4];
    const float* relb = (const float*)d_in[5];
    float* out = (float*)d_out;

    _Float16* w1T = (_Float16*)((char*)d_ws);
    _Float16* w2T = (_Float16*)((char*)d_ws + WS_W2T);
    float*    b1p = (float*)((char*)d_ws + WS_B1P);
    float*    tbl = (float*)((char*)d_ws + WS_TBL);

    swin_prep_kernel<<<210, 256, 0, stream>>>(w1, b1, w2, relb, w1T, w2T, b1p, tbl);
    swin_attn_kernel<<<4096, 256, 0, stream>>>(x, w1T, w2T, b1p, b2, tbl, out);
}